// Round 1
// 198.857 us; speedup vs baseline: 1.0303x; 1.0303x over previous
//
#include <hip/hip_runtime.h>
#include <cmath>

#define BB 2
#define TT 2048
#define NN 16
#define DD 128
#define NROWS (BB*TT*NN)          // 65536 rows of 128
#define PLANE (TT*DD)             // elements per (b,n) plane
#define KP 132                    // Ks/Xs/Ws pitch (u16): 66 dw == 2 mod 32
#define VP 68                     // Vt pitch (u16): 34 dw == 2 mod 32

typedef unsigned short u16;
typedef unsigned int   u32;
typedef __attribute__((ext_vector_type(8)))  short s8v;   // 8 bf16 = 4 VGPRs
typedef __attribute__((ext_vector_type(16))) float vf16;  // MFMA 32x32 acc

// Static device-global scratch (no ws_size assumptions — round-3 lesson).
__device__ u16 g_Q [(size_t)NROWS * DD];   // (b,n,t,d) bf16 (pre-scaled); overwritten by att
__device__ u16 g_K [(size_t)NROWS * DD];   // (b,n,t,d) bf16
__device__ u16 g_V [(size_t)NROWS * DD];   // (b,n,t,d) bf16
__device__ u16 g_VT[(size_t)NROWS * DD];   // (b,n,d,t) bf16 = V transposed

__device__ __forceinline__ u16 f2bf(float f) {          // round-half-up, 2 ops
    return (u16)((__float_as_uint(f) + 0x8000u) >> 16);
}
__device__ __forceinline__ u32 pk2(float a, float b) {  // pack 2 bf16
    return ((__float_as_uint(a) + 0x8000u) >> 16)
         | ((__float_as_uint(b) + 0x8000u) & 0xFFFF0000u);
}
__device__ __forceinline__ void st8(u16* p, const float4& a, const float4& b) {
    uint2 lo, hi;
    lo.x = pk2(a.x, a.y); lo.y = pk2(a.z, a.w);
    hi.x = pk2(b.x, b.y); hi.y = pk2(b.z, b.w);
    *(uint2*)p       = lo;
    *(uint2*)(p + 4) = hi;
}
__device__ __forceinline__ s8v ld8(const u16* p) {      // two aligned b64 reads
    short4 a = *(const short4*)p;
    short4 b = *(const short4*)(p + 4);
    return (s8v){a.x, a.y, a.z, a.w, b.x, b.y, b.z, b.w};
}

// ---------------------------------------------------------------------------
// Fused QKV projection: x fp32 rows (b,t,n) -> bf16 Q/K/V rows (b,n,t).
// Q is written pre-scaled by (1/sqrt(D))*log2(e) so attention softmax runs in
// exp2 domain with no per-element scale mul.
// ---------------------------------------------------------------------------
__global__ __launch_bounds__(256)
void qkv_proj_kernel(const float* __restrict__ x,
                     const float* __restrict__ Wq, const float* __restrict__ Bq,
                     const float* __restrict__ Wk, const float* __restrict__ Bk,
                     const float* __restrict__ Wv, const float* __restrict__ Bv)
{
    __shared__ u16 Xs[128*KP];
    __shared__ u16 Ws[128*KP];

    const int t  = threadIdx.x;
    const int r0 = blockIdx.x * 128;
    const float4* xsrc = (const float4*)(x + (size_t)r0*DD);

    // stage X tile (fp32 -> bf16)
    #pragma unroll
    for (int it = 0; it < 8; ++it) {
        int i = t + 256*it;             // 2048 chunks of 8
        int e = i >> 4, c8 = i & 15;
        st8(&Xs[e*KP + c8*8], xsrc[2*i], xsrc[2*i + 1]);
    }
    // stage W for wsel=0
    #pragma unroll
    for (int it = 0; it < 8; ++it) {
        int i = t + 256*it;
        int e = i >> 4, c8 = i & 15;
        st8(&Ws[e*KP + c8*8], ((const float4*)Wq)[2*i], ((const float4*)Wq)[2*i + 1]);
    }
    __syncthreads();

    const int w   = t >> 6;
    const int l31 = t & 31;
    const int q2  = (t >> 5) & 1;

    // A-fragments: this wave's 32-row band, in registers for all 3 GEMMs
    s8v af[8];
    #pragma unroll
    for (int s = 0; s < 8; ++s)
        af[s] = ld8(&Xs[(w*32 + l31)*KP + s*16 + q2*8]);

    #pragma unroll
    for (int wsel = 0; wsel < 3; ++wsel) {
        const float* Bi = (wsel == 0) ? Bq : (wsel == 1) ? Bk : Bv;
        u16*         Ot = (wsel == 0) ? g_Q : (wsel == 1) ? g_K : g_V;

        vf16 acc[4];
        #pragma unroll
        for (int et = 0; et < 4; ++et)
            #pragma unroll
            for (int i = 0; i < 16; ++i) acc[et][i] = 0.f;

        #pragma unroll
        for (int s = 0; s < 8; ++s) {
            #pragma unroll
            for (int et = 0; et < 4; ++et) {
                s8v bf = ld8(&Ws[(et*32 + l31)*KP + s*16 + q2*8]);
                acc[et] = __builtin_amdgcn_mfma_f32_32x32x16_bf16(af[s], bf, acc[et], 0, 0, 0);
            }
        }

        float bb[4];
        #pragma unroll
        for (int et = 0; et < 4; ++et) bb[et] = Bi[et*32 + l31];

        #pragma unroll
        for (int r = 0; r < 16; ++r) {
            int rl = (r & 3) + 8*(r >> 2) + 4*q2;
            int rg = r0 + w*32 + rl;
            int b = rg >> 15, rem = rg & 32767;   // (b,t,n) -> (b,n,t)
            int tt = rem >> 4, n = rem & 15;
            size_t orow = (size_t)((b*NN + n)*TT + tt) * DD;
            #pragma unroll
            for (int et = 0; et < 4; ++et) {
                float ov = acc[et][r] + bb[et];
                if (wsel == 0) ov *= 0.12752053685940512f;  // (1/sqrt(128))*log2(e)
                Ot[orow + et*32 + l31] = f2bf(ov);
            }
        }

        if (wsel < 2) {
            const float* Wn = (wsel == 0) ? Wk : Wv;
            __syncthreads();             // everyone done reading Ws
            #pragma unroll
            for (int it = 0; it < 8; ++it) {
                int i = t + 256*it;
                int e = i >> 4, c8 = i & 15;
                st8(&Ws[e*KP + c8*8], ((const float4*)Wn)[2*i], ((const float4*)Wn)[2*i + 1]);
            }
            __syncthreads();
        }
    }
}

// ---------------------------------------------------------------------------
// Output projection: bf16 att rows (b,n,t) in g_Q -> fp32 out (b,t,n).
// ---------------------------------------------------------------------------
__global__ __launch_bounds__(256)
void out_proj_kernel(const float* __restrict__ W, const float* __restrict__ Bi,
                     float* __restrict__ out)
{
    __shared__ u16 Ws[128*KP];

    const int t  = threadIdx.x;
    const int r0 = blockIdx.x * 128;

    #pragma unroll
    for (int it = 0; it < 8; ++it) {
        int i = t + 256*it;
        int e = i >> 4, c8 = i & 15;
        st8(&Ws[e*KP + c8*8], ((const float4*)W)[2*i], ((const float4*)W)[2*i + 1]);
    }

    const int w   = t >> 6;
    const int l31 = t & 31;
    const int q2  = (t >> 5) & 1;

    s8v af[8];
    {
        const u16* src = g_Q + (size_t)(r0 + w*32 + l31)*DD;
        #pragma unroll
        for (int s = 0; s < 8; ++s)
            af[s] = *(const s8v*)&src[s*16 + q2*8];
    }
    __syncthreads();

    vf16 acc[4];
    #pragma unroll
    for (int et = 0; et < 4; ++et)
        #pragma unroll
        for (int i = 0; i < 16; ++i) acc[et][i] = 0.f;

    #pragma unroll
    for (int s = 0; s < 8; ++s) {
        #pragma unroll
        for (int et = 0; et < 4; ++et) {
            s8v bf = ld8(&Ws[(et*32 + l31)*KP + s*16 + q2*8]);
            acc[et] = __builtin_amdgcn_mfma_f32_32x32x16_bf16(af[s], bf, acc[et], 0, 0, 0);
        }
    }

    float bb[4];
    #pragma unroll
    for (int et = 0; et < 4; ++et) bb[et] = Bi[et*32 + l31];

    #pragma unroll
    for (int r = 0; r < 16; ++r) {
        int rl = (r & 3) + 8*(r >> 2) + 4*q2;
        int rg = r0 + w*32 + rl;
        int b = rg >> 15, rem = rg & 32767;   // (b,n,t) -> (b,t,n)
        int n = rem >> 11, tt = rem & 2047;
        size_t orow = (size_t)((b*TT + tt)*NN + n) * DD;
        #pragma unroll
        for (int et = 0; et < 4; ++et)
            out[orow + et*32 + l31] = acc[et][r] + bb[et];
    }
}

// ---------------------------------------------------------------------------
// V transpose via LDS tile: g_V (b,n,t,d) -> g_VT (b,n,d,t).
// Coalesced uint4 reads AND writes (old version had 2B stride-256B reads).
// Tile = 64 t x 128 d; 1024 blocks.
// ---------------------------------------------------------------------------
__global__ __launch_bounds__(256)
void vtrans_kernel()
{
    __shared__ u16 L[64*KP];   // 64 t-rows, pitch 132 u16 (rows 16B-aligned)

    const int t   = threadIdx.x;
    const int blk = blockIdx.x;            // 32 planes x 32 t-tiles
    const int pl  = blk >> 5;
    const int tt0 = (blk & 31) * 64;
    const size_t plane = (size_t)pl * PLANE;

    #pragma unroll
    for (int c = 0; c < 4; ++c) {
        int j = t + 256*c;                  // 0..1023
        int row = j >> 4, c16 = j & 15;
        uint4 v = *(const uint4*)&g_V[plane + (size_t)(tt0 + row)*DD + c16*8];
        *(uint4*)&L[row*KP + c16*8] = v;
    }
    __syncthreads();
    #pragma unroll
    for (int c = 0; c < 4; ++c) {
        int j = t + 256*c;
        int d = j >> 3, tc = j & 7;
        u16 e[8];
        #pragma unroll
        for (int i = 0; i < 8; ++i) e[i] = L[(tc*8 + i)*KP + d];
        uint4 pkv;
        pkv.x = (u32)e[0] | ((u32)e[1] << 16);
        pkv.y = (u32)e[2] | ((u32)e[3] << 16);
        pkv.z = (u32)e[4] | ((u32)e[5] << 16);
        pkv.w = (u32)e[6] | ((u32)e[7] << 16);
        *(uint4*)&g_VT[plane + (size_t)d*TT + tt0 + tc*8] = pkv;
    }
}

// ---------------------------------------------------------------------------
// MFMA flash attention, re-gridded for sustained occupancy:
//   block = (bn, q-tile 64) = 2 waves x 32-q bands, 128 threads, K-tile 64.
//   1024 blocks; LDS 34.3KB -> 4 blocks/CU co-resident = 8 waves/CU steady.
//   Quadruple pairing: co-resident blocks c,c+256,c+512,c+768 have
//   nkt = {32-g, g+1, 24-g, g+9} (sum 66, uniform) and share bn (L2 reuse).
//   At q-tile 64 the causal fit is exact: no fully-masked wave-tiles.
//   Q comes in pre-scaled (exp2 domain). Defer-max rescale (THR=8).
// ---------------------------------------------------------------------------
__global__ __launch_bounds__(128, 2)
void attn_kernel()
{
    __shared__ u16 Ks[64*KP];
    __shared__ u16 Vt[128*VP];

    const int t   = threadIdx.x;              // 0..127
    const int grp = blockIdx.x >> 5;          // 0..31
    const int bn  = blockIdx.x & 31;
    int qt;
    if      (grp < 8)  qt = 31 - grp;         // 31..24 heavy
    else if (grp < 16) qt = grp - 8;          // 0..7   light
    else if (grp < 24) qt = 39 - grp;         // 23..16 mid-heavy
    else               qt = grp - 16;         // 8..15  mid-light

    const size_t plane = (size_t)bn * PLANE;
    const u16* Kg = g_K  + plane;
    const u16* Vg = g_VT + plane;

    const int w      = t >> 6;                // 0..1
    const int lane   = t & 63;
    const int lane31 = lane & 31;
    const int q2     = lane >> 5;
    const int qband  = qt*64 + 32*w;
    const int qrow   = qband + lane31;

    s8v qf[8];
    {
        const u16* Qg = g_Q + plane + (size_t)qrow * DD;
        #pragma unroll
        for (int s = 0; s < 8; ++s)
            qf[s] = *(const s8v*)&Qg[s*16 + q2*8];
    }

    vf16 accO[4];
    #pragma unroll
    for (int dt = 0; dt < 4; ++dt)
        #pragma unroll
        for (int i = 0; i < 16; ++i) accO[dt][i] = 0.f;

    float mrow = -INFINITY, lrow = 0.f;

    const int nkt = qt + 1;

    // prefetch tile 0 into registers (16 uint4/thread)
    uint4 pk[8], pv[8];
    #pragma unroll
    for (int c = 0; c < 8; ++c) {
        int j = t + 128*c;
        int kr = j >> 4, kc = j & 15;
        pk[c] = *(const uint4*)&Kg[kr*DD + kc*8];
        int vr = j >> 3, vc = j & 7;
        pv[c] = *(const uint4*)&Vg[(size_t)vr*TT + vc*8];
    }

    for (int kt = 0; kt < nkt; ++kt) {
        const int k0 = kt*64;
        __syncthreads();                      // prev iter done with LDS
        // write prefetched tile to LDS (aligned b64 stores)
        #pragma unroll
        for (int c = 0; c < 8; ++c) {
            int j = t + 128*c;
            int kr = j >> 4, kc = j & 15;
            uint2 a, b;
            a.x = pk[c].x; a.y = pk[c].y; b.x = pk[c].z; b.y = pk[c].w;
            *(uint2*)&Ks[kr*KP + kc*8]     = a;
            *(uint2*)&Ks[kr*KP + kc*8 + 4] = b;
            int vr = j >> 3, vc = j & 7;
            a.x = pv[c].x; a.y = pv[c].y; b.x = pv[c].z; b.y = pv[c].w;
            *(uint2*)&Vt[vr*VP + vc*8]     = a;
            *(uint2*)&Vt[vr*VP + vc*8 + 4] = b;
        }
        __syncthreads();

        // issue next tile's global loads now; latency hides behind compute
        if (kt + 1 < nkt) {
            const u16* Kg2 = Kg + (size_t)(k0 + 64)*DD;
            const u16* Vg2 = Vg + (k0 + 64);
            #pragma unroll
            for (int c = 0; c < 8; ++c) {
                int j = t + 128*c;
                int kr = j >> 4, kc = j & 15;
                pk[c] = *(const uint4*)&Kg2[kr*DD + kc*8];
                int vr = j >> 3, vc = j & 7;
                pv[c] = *(const uint4*)&Vg2[(size_t)vr*TT + vc*8];
            }
        }

        // ---- S^T = K · Q^T (Q pre-scaled: output already in exp2 domain) ----
        vf16 accS[2];
        #pragma unroll
        for (int kk = 0; kk < 2; ++kk)
            #pragma unroll
            for (int i = 0; i < 16; ++i) accS[kk][i] = 0.f;
        __builtin_amdgcn_s_setprio(1);
        #pragma unroll
        for (int s = 0; s < 8; ++s) {
            #pragma unroll
            for (int kk = 0; kk < 2; ++kk) {
                s8v a = ld8(&Ks[(kk*32 + lane31)*KP + s*16 + q2*8]);
                accS[kk] = __builtin_amdgcn_mfma_f32_32x32x16_bf16(a, qf[s], accS[kk], 0, 0, 0);
            }
        }
        __builtin_amdgcn_s_setprio(0);

        // ---- causal mask (tail tile only) ----
        float p[2][16];
        const bool tail = (kt == qt);
        #pragma unroll
        for (int kk = 0; kk < 2; ++kk)
            #pragma unroll
            for (int r = 0; r < 16; ++r) {
                float sv = accS[kk][r];
                if (tail) {
                    int keyg = k0 + kk*32 + (r & 3) + 8*(r >> 2) + 4*q2;
                    if (keyg > qrow) sv = -INFINITY;
                }
                p[kk][r] = sv;
            }

        // ---- online softmax with defer-max (THR=8) ----
        float v0 = -INFINITY, v1 = -INFINITY;
        #pragma unroll
        for (int r = 0; r < 16; ++r) {
            v0 = fmaxf(v0, p[0][r]);
            v1 = fmaxf(v1, p[1][r]);
        }
        float vmax = fmaxf(v0, v1);
        vmax = fmaxf(vmax, __shfl_xor(vmax, 32));

        if (!__all(vmax <= mrow + 8.f)) {     // rescale rarely taken
            float mnew  = fmaxf(mrow, vmax);
            float alpha = __builtin_amdgcn_exp2f(mrow - mnew);
            lrow *= alpha;
            float ar[16];
            #pragma unroll
            for (int r = 0; r < 16; ++r)
                ar[r] = __shfl(alpha, (r & 3) + 8*(r >> 2) + 4*q2);
            #pragma unroll
            for (int dt = 0; dt < 4; ++dt)
                #pragma unroll
                for (int r = 0; r < 16; ++r) accO[dt][r] *= ar[r];
            mrow = mnew;
        }

        float ls0 = 0.f, ls1 = 0.f;
        #pragma unroll
        for (int r = 0; r < 16; ++r) {
            float e0 = __builtin_amdgcn_exp2f(p[0][r] - mrow);
            float e1 = __builtin_amdgcn_exp2f(p[1][r] - mrow);
            p[0][r] = e0; p[1][r] = e1;
            ls0 += e0; ls1 += e1;
        }
        float ls = ls0 + ls1;
        ls += __shfl_xor(ls, 32);
        lrow += ls;

        // ---- pack P (bf16 trunc) as PV A-fragments ----
        s8v pf[4];
        #pragma unroll
        for (int tau = 0; tau < 4; ++tau) {
            int kk = tau >> 1, rb = (tau & 1)*8;
            s8v v;
            #pragma unroll
            for (int j = 0; j < 8; ++j)
                v[j] = (short)(__float_as_uint(p[kk][rb + j]) >> 16);
            pf[tau] = v;
        }

        // ---- O += P · V ----
        __builtin_amdgcn_s_setprio(1);
        #pragma unroll
        for (int dt = 0; dt < 4; ++dt) {
            const u16* vp = &Vt[(dt*32 + lane31)*VP];
            #pragma unroll
            for (int tau = 0; tau < 4; ++tau) {
                const u16* q = vp + 16*tau + 4*q2;
                short4 lo = *(const short4*)q;
                short4 hi = *(const short4*)(q + 8);
                s8v bvv = {lo.x, lo.y, lo.z, lo.w, hi.x, hi.y, hi.z, hi.w};
                accO[dt] = __builtin_amdgcn_mfma_f32_32x32x16_bf16(pf[tau], bvv, accO[dt], 0, 0, 0);
            }
        }
        __builtin_amdgcn_s_setprio(0);
    }

    // ---- epilogue: normalize, write bf16 O over own g_Q rows ----
    float inv = 1.0f / lrow;
    #pragma unroll
    for (int r = 0; r < 16; ++r) {
        int rl = (r & 3) + 8*(r >> 2) + 4*q2;
        float ir = __shfl(inv, rl);
        u16* op = g_Q + plane + (size_t)(qband + rl)*DD;
        #pragma unroll
        for (int dt = 0; dt < 4; ++dt)
            op[dt*32 + lane31] = f2bf(accO[dt][r] * ir);
    }
}

extern "C" void kernel_launch(void* const* d_in, const int* in_sizes, int n_in,
                              void* d_out, int out_size, void* d_ws, size_t ws_size,
                              hipStream_t stream)
{
    const float* x  = (const float*)d_in[0];
    const float* wq = (const float*)d_in[1];
    const float* bq = (const float*)d_in[2];
    const float* wk = (const float*)d_in[3];
    const float* bk = (const float*)d_in[4];
    const float* wv = (const float*)d_in[5];
    const float* bv = (const float*)d_in[6];
    const float* wp = (const float*)d_in[7];
    const float* bp = (const float*)d_in[8];
    float* out = (float*)d_out;
    (void)d_ws; (void)ws_size;

    qkv_proj_kernel<<<dim3(NROWS/128), dim3(256), 0, stream>>>(
        x, wq, bq, wk, bk, wv, bv);
    vtrans_kernel<<<dim3(BB*NN*(TT/64)), dim3(256), 0, stream>>>();
    attn_kernel<<<dim3(BB*NN*(TT/64)), dim3(128), 0, stream>>>();
    out_proj_kernel<<<dim3(NROWS/128), dim3(256), 0, stream>>>(wp, bp, out);
}

// Round 2
// 196.224 us; speedup vs baseline: 1.0441x; 1.0134x over previous
//
#include <hip/hip_runtime.h>
#include <cmath>

#define BB 2
#define TT 2048
#define NN 16
#define DD 128
#define NROWS (BB*TT*NN)          // 65536 rows of 128
#define PLANE (TT*DD)             // elements per (b,n) plane
#define KP 132                    // Ks/Xs/Ws pitch (u16): 66 dw == 2 mod 32
#define VP 68                     // Vt pitch (u16): 34 dw == 2 mod 32

typedef unsigned short u16;
typedef unsigned int   u32;
typedef __attribute__((ext_vector_type(8)))  short s8v;   // 8 bf16 = 4 VGPRs
typedef __attribute__((ext_vector_type(16))) float vf16;  // MFMA 32x32 acc

// Static device-global scratch (no ws_size assumptions — round-3 lesson).
__device__ u16 g_Q [(size_t)NROWS * DD];   // (b,n,t,d) bf16 (pre-scaled); overwritten by att
__device__ u16 g_K [(size_t)NROWS * DD];   // (b,n,t,d) bf16
__device__ u16 g_V [(size_t)NROWS * DD];   // (b,n,t,d) bf16
__device__ u16 g_VT[(size_t)NROWS * DD];   // (b,n,d,t) bf16 = V transposed

__device__ __forceinline__ u16 f2bf(float f) {          // round-half-up, 2 ops
    return (u16)((__float_as_uint(f) + 0x8000u) >> 16);
}
__device__ __forceinline__ u32 pk2(float a, float b) {  // pack 2 bf16
    return ((__float_as_uint(a) + 0x8000u) >> 16)
         | ((__float_as_uint(b) + 0x8000u) & 0xFFFF0000u);
}
__device__ __forceinline__ void st8(u16* p, const float4& a, const float4& b) {
    uint2 lo, hi;
    lo.x = pk2(a.x, a.y); lo.y = pk2(a.z, a.w);
    hi.x = pk2(b.x, b.y); hi.y = pk2(b.z, b.w);
    *(uint2*)p       = lo;
    *(uint2*)(p + 4) = hi;
}
__device__ __forceinline__ s8v ld8(const u16* p) {      // two aligned b64 reads
    short4 a = *(const short4*)p;
    short4 b = *(const short4*)(p + 4);
    return (s8v){a.x, a.y, a.z, a.w, b.x, b.y, b.z, b.w};
}

// ---------------------------------------------------------------------------
// Fused QKV projection: x fp32 rows (b,t,n) -> bf16 Q/K/V rows (b,n,t).
// Q is written pre-scaled by (1/sqrt(D))*log2(e) so attention softmax runs in
// exp2 domain with no per-element scale mul.
// ---------------------------------------------------------------------------
__global__ __launch_bounds__(256)
void qkv_proj_kernel(const float* __restrict__ x,
                     const float* __restrict__ Wq, const float* __restrict__ Bq,
                     const float* __restrict__ Wk, const float* __restrict__ Bk,
                     const float* __restrict__ Wv, const float* __restrict__ Bv)
{
    __shared__ u16 Xs[128*KP];
    __shared__ u16 Ws[128*KP];

    const int t  = threadIdx.x;
    const int r0 = blockIdx.x * 128;
    const float4* xsrc = (const float4*)(x + (size_t)r0*DD);

    // stage X tile (fp32 -> bf16)
    #pragma unroll
    for (int it = 0; it < 8; ++it) {
        int i = t + 256*it;             // 2048 chunks of 8
        int e = i >> 4, c8 = i & 15;
        st8(&Xs[e*KP + c8*8], xsrc[2*i], xsrc[2*i + 1]);
    }
    // stage W for wsel=0
    #pragma unroll
    for (int it = 0; it < 8; ++it) {
        int i = t + 256*it;
        int e = i >> 4, c8 = i & 15;
        st8(&Ws[e*KP + c8*8], ((const float4*)Wq)[2*i], ((const float4*)Wq)[2*i + 1]);
    }
    __syncthreads();

    const int w   = t >> 6;
    const int l31 = t & 31;
    const int q2  = (t >> 5) & 1;

    // A-fragments: this wave's 32-row band, in registers for all 3 GEMMs
    s8v af[8];
    #pragma unroll
    for (int s = 0; s < 8; ++s)
        af[s] = ld8(&Xs[(w*32 + l31)*KP + s*16 + q2*8]);

    #pragma unroll
    for (int wsel = 0; wsel < 3; ++wsel) {
        const float* Bi = (wsel == 0) ? Bq : (wsel == 1) ? Bk : Bv;
        u16*         Ot = (wsel == 0) ? g_Q : (wsel == 1) ? g_K : g_V;

        vf16 acc[4];
        #pragma unroll
        for (int et = 0; et < 4; ++et)
            #pragma unroll
            for (int i = 0; i < 16; ++i) acc[et][i] = 0.f;

        #pragma unroll
        for (int s = 0; s < 8; ++s) {
            #pragma unroll
            for (int et = 0; et < 4; ++et) {
                s8v bf = ld8(&Ws[(et*32 + l31)*KP + s*16 + q2*8]);
                acc[et] = __builtin_amdgcn_mfma_f32_32x32x16_bf16(af[s], bf, acc[et], 0, 0, 0);
            }
        }

        float bb[4];
        #pragma unroll
        for (int et = 0; et < 4; ++et) bb[et] = Bi[et*32 + l31];

        #pragma unroll
        for (int r = 0; r < 16; ++r) {
            int rl = (r & 3) + 8*(r >> 2) + 4*q2;
            int rg = r0 + w*32 + rl;
            int b = rg >> 15, rem = rg & 32767;   // (b,t,n) -> (b,n,t)
            int tt = rem >> 4, n = rem & 15;
            size_t orow = (size_t)((b*NN + n)*TT + tt) * DD;
            #pragma unroll
            for (int et = 0; et < 4; ++et) {
                float ov = acc[et][r] + bb[et];
                if (wsel == 0) ov *= 0.12752053685940512f;  // (1/sqrt(128))*log2(e)
                Ot[orow + et*32 + l31] = f2bf(ov);
            }
        }

        if (wsel < 2) {
            const float* Wn = (wsel == 0) ? Wk : Wv;
            __syncthreads();             // everyone done reading Ws
            #pragma unroll
            for (int it = 0; it < 8; ++it) {
                int i = t + 256*it;
                int e = i >> 4, c8 = i & 15;
                st8(&Ws[e*KP + c8*8], ((const float4*)Wn)[2*i], ((const float4*)Wn)[2*i + 1]);
            }
            __syncthreads();
        }
    }
}

// ---------------------------------------------------------------------------
// Output projection: bf16 att rows (b,n,t) in g_Q -> fp32 out (b,t,n).
// ---------------------------------------------------------------------------
__global__ __launch_bounds__(256)
void out_proj_kernel(const float* __restrict__ W, const float* __restrict__ Bi,
                     float* __restrict__ out)
{
    __shared__ u16 Ws[128*KP];

    const int t  = threadIdx.x;
    const int r0 = blockIdx.x * 128;

    #pragma unroll
    for (int it = 0; it < 8; ++it) {
        int i = t + 256*it;
        int e = i >> 4, c8 = i & 15;
        st8(&Ws[e*KP + c8*8], ((const float4*)W)[2*i], ((const float4*)W)[2*i + 1]);
    }

    const int w   = t >> 6;
    const int l31 = t & 31;
    const int q2  = (t >> 5) & 1;

    s8v af[8];
    {
        const u16* src = g_Q + (size_t)(r0 + w*32 + l31)*DD;
        #pragma unroll
        for (int s = 0; s < 8; ++s)
            af[s] = *(const s8v*)&src[s*16 + q2*8];
    }
    __syncthreads();

    vf16 acc[4];
    #pragma unroll
    for (int et = 0; et < 4; ++et)
        #pragma unroll
        for (int i = 0; i < 16; ++i) acc[et][i] = 0.f;

    #pragma unroll
    for (int s = 0; s < 8; ++s) {
        #pragma unroll
        for (int et = 0; et < 4; ++et) {
            s8v bf = ld8(&Ws[(et*32 + l31)*KP + s*16 + q2*8]);
            acc[et] = __builtin_amdgcn_mfma_f32_32x32x16_bf16(af[s], bf, acc[et], 0, 0, 0);
        }
    }

    float bb[4];
    #pragma unroll
    for (int et = 0; et < 4; ++et) bb[et] = Bi[et*32 + l31];

    #pragma unroll
    for (int r = 0; r < 16; ++r) {
        int rl = (r & 3) + 8*(r >> 2) + 4*q2;
        int rg = r0 + w*32 + rl;
        int b = rg >> 15, rem = rg & 32767;   // (b,n,t) -> (b,t,n)
        int n = rem >> 11, tt = rem & 2047;
        size_t orow = (size_t)((b*TT + tt)*NN + n) * DD;
        #pragma unroll
        for (int et = 0; et < 4; ++et)
            out[orow + et*32 + l31] = acc[et][r] + bb[et];
    }
}

// ---------------------------------------------------------------------------
// V transpose via LDS tile: g_V (b,n,t,d) -> g_VT (b,n,d,t).
// ---------------------------------------------------------------------------
__global__ __launch_bounds__(256)
void vtrans_kernel()
{
    __shared__ u16 L[64*KP];   // 64 t-rows, pitch 132 u16 (rows 16B-aligned)

    const int t   = threadIdx.x;
    const int blk = blockIdx.x;            // 32 planes x 32 t-tiles
    const int pl  = blk >> 5;
    const int tt0 = (blk & 31) * 64;
    const size_t plane = (size_t)pl * PLANE;

    #pragma unroll
    for (int c = 0; c < 4; ++c) {
        int j = t + 256*c;                  // 0..1023
        int row = j >> 4, c16 = j & 15;
        uint4 v = *(const uint4*)&g_V[plane + (size_t)(tt0 + row)*DD + c16*8];
        *(uint4*)&L[row*KP + c16*8] = v;
    }
    __syncthreads();
    #pragma unroll
    for (int c = 0; c < 4; ++c) {
        int j = t + 256*c;
        int d = j >> 3, tc = j & 7;
        u16 e[8];
        #pragma unroll
        for (int i = 0; i < 8; ++i) e[i] = L[(tc*8 + i)*KP + d];
        uint4 pkv;
        pkv.x = (u32)e[0] | ((u32)e[1] << 16);
        pkv.y = (u32)e[2] | ((u32)e[3] << 16);
        pkv.z = (u32)e[4] | ((u32)e[5] << 16);
        pkv.w = (u32)e[6] | ((u32)e[7] << 16);
        *(uint4*)&g_VT[plane + (size_t)d*TT + tt0 + tc*8] = pkv;
    }
}

// ---------------------------------------------------------------------------
// MFMA flash attention, double-buffered LDS, ONE barrier per K-tile:
//   prologue: load t0->regs, write buf0, load t1->regs
//   loop kt:  barrier -> compute buf[kt&1] -> write regs->buf[kt+1 &1]
//             -> issue loads for tile kt+2 (in flight across barrier+compute)
// Block = (bn, q-tile 128) = 4 waves x 32-q bands; K-tile 64.
// LDS 68.6 KB -> 2 blocks/CU (8 waves/CU); heavy+light pairing keeps per-CU
// work uniform (nkt sums to 36 for co-resident pair c, c+256; same bn -> L2).
// Q pre-scaled (exp2 domain); defer-max rescale (THR=8); setprio on MFMA.
// ---------------------------------------------------------------------------
__global__ __launch_bounds__(256, 2)
void attn_kernel()
{
    __shared__ u16 Ks[2][64*KP];
    __shared__ u16 Vt[2][128*VP];

    const int t   = threadIdx.x;
    const int grp = blockIdx.x >> 5;              // 0..15
    const int bn  = blockIdx.x & 31;
    const int qt  = (grp < 8) ? (15 - grp) : (grp - 8);  // uniform-sum pairs
    const int q0  = qt * 128;
    const size_t plane = (size_t)bn * PLANE;
    const u16* Kg = g_K  + plane;
    const u16* Vg = g_VT + plane;

    const int w      = t >> 6;
    const int lane   = t & 63;
    const int lane31 = lane & 31;
    const int q2     = lane >> 5;
    const int qband  = q0 + 32*w;
    const int qrow   = qband + lane31;

    s8v qf[8];
    {
        const u16* Qg = g_Q + plane + (size_t)qrow * DD;
        #pragma unroll
        for (int s = 0; s < 8; ++s)
            qf[s] = *(const s8v*)&Qg[s*16 + q2*8];
    }

    vf16 accO[4];
    #pragma unroll
    for (int dt = 0; dt < 4; ++dt)
        #pragma unroll
        for (int i = 0; i < 16; ++i) accO[dt][i] = 0.f;

    float mrow = -INFINITY, lrow = 0.f;
    const int nkt = 2*qt + 2;

    uint4 pk[4], pv[4];

    // ---- prologue: tile 0 -> regs -> buf0; tile 1 -> regs (in flight) ----
    #pragma unroll
    for (int c = 0; c < 4; ++c) {
        int j = t + 256*c;
        int kr = j >> 4, kc = j & 15;
        pk[c] = *(const uint4*)&Kg[kr*DD + kc*8];
        int vr = j >> 3, vc = j & 7;
        pv[c] = *(const uint4*)&Vg[(size_t)vr*TT + vc*8];
    }
    #pragma unroll
    for (int c = 0; c < 4; ++c) {
        int j = t + 256*c;
        int kr = j >> 4, kc = j & 15;
        uint2 a, b;
        a.x = pk[c].x; a.y = pk[c].y; b.x = pk[c].z; b.y = pk[c].w;
        *(uint2*)&Ks[0][kr*KP + kc*8]     = a;
        *(uint2*)&Ks[0][kr*KP + kc*8 + 4] = b;
        int vr = j >> 3, vc = j & 7;
        a.x = pv[c].x; a.y = pv[c].y; b.x = pv[c].z; b.y = pv[c].w;
        *(uint2*)&Vt[0][vr*VP + vc*8]     = a;
        *(uint2*)&Vt[0][vr*VP + vc*8 + 4] = b;
    }
    {
        const u16* Kg2 = Kg + (size_t)64*DD;
        const u16* Vg2 = Vg + 64;
        #pragma unroll
        for (int c = 0; c < 4; ++c) {
            int j = t + 256*c;
            int kr = j >> 4, kc = j & 15;
            pk[c] = *(const uint4*)&Kg2[kr*DD + kc*8];
            int vr = j >> 3, vc = j & 7;
            pv[c] = *(const uint4*)&Vg2[(size_t)vr*TT + vc*8];
        }
    }

    for (int kt = 0; kt < nkt; ++kt) {
        const int k0 = kt*64;
        __syncthreads();              // buf[kt&1] staged; buf[kt+1&1] free
        const u16* Kb = Ks[kt & 1];
        const u16* Vb = Vt[kt & 1];

        if (k0 <= qband + 31) {
            // ---- S^T = K · Q^T (Q pre-scaled: already in exp2 domain) ----
            vf16 accS[2];
            #pragma unroll
            for (int kk = 0; kk < 2; ++kk)
                #pragma unroll
                for (int i = 0; i < 16; ++i) accS[kk][i] = 0.f;
            __builtin_amdgcn_s_setprio(1);
            #pragma unroll
            for (int s = 0; s < 8; ++s) {
                #pragma unroll
                for (int kk = 0; kk < 2; ++kk) {
                    s8v a = ld8(&Kb[(kk*32 + lane31)*KP + s*16 + q2*8]);
                    accS[kk] = __builtin_amdgcn_mfma_f32_32x32x16_bf16(a, qf[s], accS[kk], 0, 0, 0);
                }
            }
            __builtin_amdgcn_s_setprio(0);

            // ---- causal mask (tail tiles only) ----
            float p[2][16];
            const bool tail = (k0 + 63 > qband);
            #pragma unroll
            for (int kk = 0; kk < 2; ++kk)
                #pragma unroll
                for (int r = 0; r < 16; ++r) {
                    float sv = accS[kk][r];
                    if (tail) {
                        int keyg = k0 + kk*32 + (r & 3) + 8*(r >> 2) + 4*q2;
                        if (keyg > qrow) sv = -INFINITY;
                    }
                    p[kk][r] = sv;
                }

            // ---- online softmax with defer-max (THR=8) ----
            float v0 = -INFINITY, v1 = -INFINITY;
            #pragma unroll
            for (int r = 0; r < 16; ++r) {
                v0 = fmaxf(v0, p[0][r]);
                v1 = fmaxf(v1, p[1][r]);
            }
            float vmax = fmaxf(v0, v1);
            vmax = fmaxf(vmax, __shfl_xor(vmax, 32));

            if (!__all(vmax <= mrow + 8.f)) {     // rescale rarely taken
                float mnew  = fmaxf(mrow, vmax);
                float alpha = __builtin_amdgcn_exp2f(mrow - mnew);
                lrow *= alpha;
                float ar[16];
                #pragma unroll
                for (int r = 0; r < 16; ++r)
                    ar[r] = __shfl(alpha, (r & 3) + 8*(r >> 2) + 4*q2);
                #pragma unroll
                for (int dt = 0; dt < 4; ++dt)
                    #pragma unroll
                    for (int r = 0; r < 16; ++r) accO[dt][r] *= ar[r];
                mrow = mnew;
            }

            float ls0 = 0.f, ls1 = 0.f;
            #pragma unroll
            for (int r = 0; r < 16; ++r) {
                float e0 = __builtin_amdgcn_exp2f(p[0][r] - mrow);
                float e1 = __builtin_amdgcn_exp2f(p[1][r] - mrow);
                p[0][r] = e0; p[1][r] = e1;
                ls0 += e0; ls1 += e1;
            }
            float ls = ls0 + ls1;
            ls += __shfl_xor(ls, 32);
            lrow += ls;

            // ---- pack P (bf16 trunc) as PV A-fragments ----
            s8v pf[4];
            #pragma unroll
            for (int tau = 0; tau < 4; ++tau) {
                int kk = tau >> 1, rb = (tau & 1)*8;
                s8v v;
                #pragma unroll
                for (int j = 0; j < 8; ++j)
                    v[j] = (short)(__float_as_uint(p[kk][rb + j]) >> 16);
                pf[tau] = v;
            }

            // ---- O += P · V ----
            __builtin_amdgcn_s_setprio(1);
            #pragma unroll
            for (int dt = 0; dt < 4; ++dt) {
                const u16* vp = &Vb[(dt*32 + lane31)*VP];
                #pragma unroll
                for (int tau = 0; tau < 4; ++tau) {
                    const u16* q = vp + 16*tau + 4*q2;
                    short4 lo = *(const short4*)q;
                    short4 hi = *(const short4*)(q + 8);
                    s8v bvv = {lo.x, lo.y, lo.z, lo.w, hi.x, hi.y, hi.z, hi.w};
                    accO[dt] = __builtin_amdgcn_mfma_f32_32x32x16_bf16(pf[tau], bvv, accO[dt], 0, 0, 0);
                }
            }
            __builtin_amdgcn_s_setprio(0);
        }

        // ---- write-late: stage prefetched tile kt+1 into the other buffer,
        //      then issue loads for tile kt+2 (in flight across next barrier)
        if (kt + 1 < nkt) {
            u16* Kw = Ks[(kt + 1) & 1];
            u16* Vw = Vt[(kt + 1) & 1];
            #pragma unroll
            for (int c = 0; c < 4; ++c) {
                int j = t + 256*c;
                int kr = j >> 4, kc = j & 15;
                uint2 a, b;
                a.x = pk[c].x; a.y = pk[c].y; b.x = pk[c].z; b.y = pk[c].w;
                *(uint2*)&Kw[kr*KP + kc*8]     = a;
                *(uint2*)&Kw[kr*KP + kc*8 + 4] = b;
                int vr = j >> 3, vc = j & 7;
                a.x = pv[c].x; a.y = pv[c].y; b.x = pv[c].z; b.y = pv[c].w;
                *(uint2*)&Vw[vr*VP + vc*8]     = a;
                *(uint2*)&Vw[vr*VP + vc*8 + 4] = b;
            }
            if (kt + 2 < nkt) {
                const u16* Kg2 = Kg + (size_t)(k0 + 128)*DD;
                const u16* Vg2 = Vg + (k0 + 128);
                #pragma unroll
                for (int c = 0; c < 4; ++c) {
                    int j = t + 256*c;
                    int kr = j >> 4, kc = j & 15;
                    pk[c] = *(const uint4*)&Kg2[kr*DD + kc*8];
                    int vr = j >> 3, vc = j & 7;
                    pv[c] = *(const uint4*)&Vg2[(size_t)vr*TT + vc*8];
                }
            }
        }
    }

    // ---- epilogue: normalize, write bf16 O over own g_Q rows ----
    float inv = 1.0f / lrow;
    #pragma unroll
    for (int r = 0; r < 16; ++r) {
        int rl = (r & 3) + 8*(r >> 2) + 4*q2;
        float ir = __shfl(inv, rl);
        u16* op = g_Q + plane + (size_t)(qband + rl)*DD;
        #pragma unroll
        for (int dt = 0; dt < 4; ++dt)
            op[dt*32 + lane31] = f2bf(accO[dt][r] * ir);
    }
}

extern "C" void kernel_launch(void* const* d_in, const int* in_sizes, int n_in,
                              void* d_out, int out_size, void* d_ws, size_t ws_size,
                              hipStream_t stream)
{
    const float* x  = (const float*)d_in[0];
    const float* wq = (const float*)d_in[1];
    const float* bq = (const float*)d_in[2];
    const float* wk = (const float*)d_in[3];
    const float* bk = (const float*)d_in[4];
    const float* wv = (const float*)d_in[5];
    const float* bv = (const float*)d_in[6];
    const float* wp = (const float*)d_in[7];
    const float* bp = (const float*)d_in[8];
    float* out = (float*)d_out;
    (void)d_ws; (void)ws_size;

    qkv_proj_kernel<<<dim3(NROWS/128), dim3(256), 0, stream>>>(
        x, wq, bq, wk, bk, wv, bv);
    vtrans_kernel<<<dim3(BB*NN*(TT/64)), dim3(256), 0, stream>>>();
    attn_kernel<<<dim3(BB*NN*(TT/128)), dim3(256), 0, stream>>>();
    out_proj_kernel<<<dim3(NROWS/128), dim3(256), 0, stream>>>(wp, bp, out);
}